// Round 9
// baseline (492.878 us; speedup 1.0000x reference)
//
#include <hip/hip_runtime.h>
#include <stdint.h>

#define TPB 256
#define NBH 2048     // histogram bins for radix levels 1,2 (11+11 bits)
#define NB3 1024     // bins for bits [9:0]
#define CAP 4096     // per-row candidate capacity (expected ~1500)
#define DCOLS 65536
#define TLOKEY 0xC0000000u   // f2key(2.0f); pivot. Fallbacks make any data correct.

typedef float f4 __attribute__((ext_vector_type(4)));

__device__ __forceinline__ unsigned f2key(float f) {
  unsigned u = __float_as_uint(f);
  unsigned m = ((int)u >> 31) | 0x80000000u;
  return u ^ m;
}
__device__ __forceinline__ float key2f(unsigned k) {
  unsigned u = (k & 0x80000000u) ? (k ^ 0x80000000u) : ~k;
  return __uint_as_float(u);
}

__device__ __forceinline__ void clear_hist(unsigned* hist, int NB) {
  for (int i = threadIdx.x; i < NB; i += TPB) hist[i] = 0u;
}

// Find, scanning bins HIGH->LOW, the bin where cumulative count (from top)
// reaches K. All threads call; ends with a barrier. 3 barriers total.
__device__ void find_top(const unsigned* hist, int NB, unsigned K,
                         unsigned* scan, unsigned* selbin, unsigned* selrem) {
  const int tid = threadIdx.x;
  const int C = NB / TPB;
  unsigned cs = 0;
  for (int i = 0; i < C; ++i) cs += hist[tid * C + i];
  scan[tid] = cs;
  __syncthreads();
  if (tid < 64) {
    unsigned e0 = scan[tid * 4 + 0], e1 = scan[tid * 4 + 1];
    unsigned e2 = scan[tid * 4 + 2], e3 = scan[tid * 4 + 3];
    unsigned s = e0 + e1 + e2 + e3;
    unsigned suff = s;
    for (int off = 1; off < 64; off <<= 1) {
      unsigned t = __shfl_down(suff, off);
      if (tid + off < 64) suff += t;
    }
    unsigned tail = suff - s;
    scan[tid * 4 + 3] = e3 + tail;
    scan[tid * 4 + 2] = e2 + e3 + tail;
    scan[tid * 4 + 1] = e1 + e2 + e3 + tail;
    scan[tid * 4 + 0] = s + tail;
  }
  __syncthreads();
  unsigned suff = scan[tid];
  unsigned above = suff - cs;
  if (above < K && suff >= K) {
    unsigned cAbove = above;
    for (int bin = tid * C + C - 1; bin >= tid * C; --bin) {
      unsigned c = hist[bin];
      if (cAbove + c >= K) { *selbin = (unsigned)bin; *selrem = K - cAbove; break; }
      cAbove += c;
    }
  }
  __syncthreads();
}

// Kernel 1: single full-row read. Writes pivot-masked output (v>=tlo ? v : 0)
// with NT stores, compacts candidates (key,idx) to LDS, flushes them to ws,
// radix-selects the exact row k-th largest, atomicMin into global threshold.
__global__ void __launch_bounds__(TPB, 4)
select_prune(const float* __restrict__ in, const int* __restrict__ kptr,
             float* __restrict__ out, unsigned* __restrict__ thr,
             unsigned* __restrict__ ncand, unsigned* __restrict__ rowbad,
             unsigned long long* __restrict__ gcand) {
  __shared__ unsigned ckey[CAP];
  __shared__ unsigned short cidx[CAP];
  __shared__ unsigned hist[NBH];
  __shared__ unsigned scan[TPB];
  __shared__ unsigned sel_bin, sel_rem, cand_cnt;

  const int tid = threadIdx.x;
  const int lane = tid & 63;
  const int row = blockIdx.x;
  const unsigned K = (unsigned)(*kptr);
  const f4* rowv = (const f4*)(in + (size_t)row * DCOLS);
  f4* outv = (f4*)(out + (size_t)row * DCOLS);
  const int n4 = DCOLS / 4;

  if (tid == 0) cand_cnt = 0u;
  __syncthreads();

  // ---- Phase C: read row once; write pivot-masked out; compact cands ----
#define CPCT(kk, ei)                                                           \
    {                                                                          \
      bool p = (kk) >= TLOKEY;                                                 \
      unsigned long long m = __ballot(p);                                      \
      if (m) {                                                                 \
        unsigned base = 0;                                                     \
        if (lane == 0) base = atomicAdd(&cand_cnt, (unsigned)__popcll(m));     \
        base = __shfl(base, 0);                                                \
        if (p) {                                                               \
          unsigned off = base + (unsigned)__popcll(m & ((1ull << lane) - 1ull));\
          if (off < CAP) { ckey[off] = (kk); cidx[off] = (unsigned short)(ei); }\
        }                                                                      \
      }                                                                        \
    }
#define PROC(v, vno)                                                           \
    {                                                                          \
      unsigned kx = f2key(v.x), ky = f2key(v.y);                               \
      unsigned kz = f2key(v.z), kw = f2key(v.w);                               \
      f4 o;                                                                    \
      o.x = (kx >= TLOKEY) ? v.x : 0.0f;                                       \
      o.y = (ky >= TLOKEY) ? v.y : 0.0f;                                       \
      o.z = (kz >= TLOKEY) ? v.z : 0.0f;                                       \
      o.w = (kw >= TLOKEY) ? v.w : 0.0f;                                       \
      __builtin_nontemporal_store(o, &outv[vno]);                              \
      bool any = (kx >= TLOKEY) | (ky >= TLOKEY) | (kz >= TLOKEY) |            \
                 (kw >= TLOKEY);                                               \
      if (__ballot(any)) {                                                     \
        CPCT(kx, (vno) * 4 + 0) CPCT(ky, (vno) * 4 + 1)                        \
        CPCT(kz, (vno) * 4 + 2) CPCT(kw, (vno) * 4 + 3)                        \
      }                                                                        \
    }
  for (int base = 0; base < n4; base += TPB * 4) {
    int i0 = base + tid;
    f4 v0 = rowv[i0];
    f4 v1 = rowv[i0 + TPB];
    f4 v2 = rowv[i0 + 2 * TPB];
    f4 v3 = rowv[i0 + 3 * TPB];
    PROC(v0, i0) PROC(v1, i0 + TPB) PROC(v2, i0 + 2 * TPB) PROC(v3, i0 + 3 * TPB)
  }
#undef PROC
#undef CPCT
  __syncthreads();
  const unsigned nc = cand_cnt;
  __syncthreads();

  // ---- Flush candidates to workspace for kernel 2 ----
  const unsigned nstore = (nc < CAP) ? nc : CAP;
  for (unsigned i = tid; i < nstore; i += TPB) {
    unsigned long long e = ((unsigned long long)ckey[i] << 32) | cidx[i];
    __builtin_nontemporal_store(e, &gcand[(size_t)row * CAP + i]);
  }
  if (tid == 0) ncand[row] = nstore;

  unsigned rk;  // this row's kth-largest as monotone key
  if (nc >= K && nc <= CAP) {
    // ---- exact 3-level radix select over LDS candidate keys ----
    clear_hist(hist, NBH); __syncthreads();
    for (unsigned i = tid; i < nc; i += TPB) atomicAdd(&hist[ckey[i] >> 21], 1u);
    __syncthreads();
    find_top(hist, NBH, K, scan, &sel_bin, &sel_rem);
    const unsigned b1 = sel_bin, K2 = sel_rem;
    __syncthreads();

    clear_hist(hist, NBH); __syncthreads();
    for (unsigned i = tid; i < nc; i += TPB) {
      unsigned kk = ckey[i];
      if ((kk >> 21) == b1) atomicAdd(&hist[(kk >> 10) & (NBH - 1)], 1u);
    }
    __syncthreads();
    find_top(hist, NBH, K2, scan, &sel_bin, &sel_rem);
    const unsigned b2 = sel_bin, K3 = sel_rem;
    __syncthreads();

    clear_hist(hist, NB3); __syncthreads();
    const unsigned pfx = (b1 << 11) | b2;
    for (unsigned i = tid; i < nc; i += TPB) {
      unsigned kk = ckey[i];
      if ((kk >> 10) == pfx) atomicAdd(&hist[kk & (NB3 - 1)], 1u);
    }
    __syncthreads();
    find_top(hist, NB3, K3, scan, &sel_bin, &sel_rem);
    rk = (b1 << 21) | (b2 << 10) | sel_bin;
  } else {
    // ---- Fallback: exact 3-pass global radix (any data); row re-masked in k2.
    if (tid == 0) rowbad[row] = 1u;
    clear_hist(hist, NBH); __syncthreads();
    for (int i = tid; i < n4; i += TPB) {
      f4 v = rowv[i];
      atomicAdd(&hist[f2key(v.x) >> 21], 1u);
      atomicAdd(&hist[f2key(v.y) >> 21], 1u);
      atomicAdd(&hist[f2key(v.z) >> 21], 1u);
      atomicAdd(&hist[f2key(v.w) >> 21], 1u);
    }
    __syncthreads();
    find_top(hist, NBH, K, scan, &sel_bin, &sel_rem);
    const unsigned b1 = sel_bin, K2 = sel_rem;
    __syncthreads();

    clear_hist(hist, NBH); __syncthreads();
    for (int i = tid; i < n4; i += TPB) {
      f4 v = rowv[i];
      unsigned kk;
      kk = f2key(v.x); if ((kk >> 21) == b1) atomicAdd(&hist[(kk >> 10) & (NBH - 1)], 1u);
      kk = f2key(v.y); if ((kk >> 21) == b1) atomicAdd(&hist[(kk >> 10) & (NBH - 1)], 1u);
      kk = f2key(v.z); if ((kk >> 21) == b1) atomicAdd(&hist[(kk >> 10) & (NBH - 1)], 1u);
      kk = f2key(v.w); if ((kk >> 21) == b1) atomicAdd(&hist[(kk >> 10) & (NBH - 1)], 1u);
    }
    __syncthreads();
    find_top(hist, NBH, K2, scan, &sel_bin, &sel_rem);
    const unsigned b2 = sel_bin, K3 = sel_rem;
    __syncthreads();

    clear_hist(hist, NB3); __syncthreads();
    const unsigned pfx = (b1 << 11) | b2;
    for (int i = tid; i < n4; i += TPB) {
      f4 v = rowv[i];
      unsigned kk;
      kk = f2key(v.x); if ((kk >> 10) == pfx) atomicAdd(&hist[kk & (NB3 - 1)], 1u);
      kk = f2key(v.y); if ((kk >> 10) == pfx) atomicAdd(&hist[kk & (NB3 - 1)], 1u);
      kk = f2key(v.z); if ((kk >> 10) == pfx) atomicAdd(&hist[kk & (NB3 - 1)], 1u);
      kk = f2key(v.w); if ((kk >> 10) == pfx) atomicAdd(&hist[kk & (NB3 - 1)], 1u);
    }
    __syncthreads();
    find_top(hist, NB3, K3, scan, &sel_bin, &sel_rem);
    rk = (b1 << 21) | (b2 << 10) | sel_bin;
  }
  if (tid == 0) atomicMin(thr, rk);
}

// Kernel 2: fix the tail. Normally only zero candidates in [tlo, thr) —
// ~500 scattered stores per row. Rare fallback (thr < tlo, or flagged row):
// full re-mask of the row (reads input from LLC).
__global__ void __launch_bounds__(TPB)
prune_tail(const float* __restrict__ in, float* __restrict__ out,
           const unsigned* __restrict__ thr, const unsigned* __restrict__ ncand,
           const unsigned* __restrict__ rowbad,
           const unsigned long long* __restrict__ gcand) {
  const int tid = threadIdx.x;
  const int row = blockIdx.x;
  const unsigned thrk = thr[0];

  if (thrk >= TLOKEY && !rowbad[row]) {
    const unsigned n = ncand[row];
    for (unsigned i = tid; i < n; i += TPB) {
      unsigned long long e = gcand[(size_t)row * CAP + i];
      if ((unsigned)(e >> 32) < thrk)
        out[(size_t)row * DCOLS + (unsigned)(e & 0xFFFFu)] = 0.0f;
    }
  } else {
    const float thrf = key2f(thrk);
    const f4* rowv = (const f4*)(in + (size_t)row * DCOLS);
    f4* outv = (f4*)(out + (size_t)row * DCOLS);
    for (int i = tid; i < DCOLS / 4; i += TPB) {
      f4 v = rowv[i];
      f4 o;
      o.x = (v.x >= thrf) ? v.x : 0.0f;
      o.y = (v.y >= thrf) ? v.y : 0.0f;
      o.z = (v.z >= thrf) ? v.z : 0.0f;
      o.w = (v.w >= thrf) ? v.w : 0.0f;
      outv[i] = o;
    }
  }
}

extern "C" void kernel_launch(void* const* d_in, const int* in_sizes, int n_in,
                              void* d_out, int out_size, void* d_ws, size_t ws_size,
                              hipStream_t stream) {
  const float* in = (const float*)d_in[0];
  const int* kptr = (const int*)d_in[1];
  float* out = (float*)d_out;

  // ws layout: thr u32 @0 | ncand u32[1024] @byte 256 | rowbad u32[1024]
  // @byte 4352 | gcand u64[1024*CAP] @byte 16384 (32 MB)
  unsigned* thr = (unsigned*)d_ws;
  unsigned* ncand = (unsigned*)d_ws + 64;
  unsigned* rowbad = (unsigned*)d_ws + 64 + 1024;
  unsigned long long* gcand = (unsigned long long*)((char*)d_ws + 16384);

  const int B = in_sizes[0] / DCOLS;   // 1024 rows

  hipMemsetAsync(thr, 0xFF, 4, stream);                  // thr = max key
  hipMemsetAsync((char*)d_ws + 256, 0, 8192, stream);    // ncand + rowbad = 0
  hipLaunchKernelGGL(select_prune, dim3(B), dim3(TPB), 0, stream,
                     in, kptr, out, thr, ncand, rowbad, gcand);
  hipLaunchKernelGGL(prune_tail, dim3(B), dim3(TPB), 0, stream,
                     in, out, thr, ncand, rowbad, gcand);
}